// Round 18
// baseline (461.919 us; speedup 1.0000x reference)
//
#include <hip/hip_runtime.h>
#include <hip/hip_bf16.h>

#define B_ 256
#define S_ 11
#define D_ 384
#define NHEAD_ 12

typedef const float* bfp;
typedef __attribute__((ext_vector_type(8))) __bf16 bf16x8;
typedef __attribute__((ext_vector_type(4))) float f32x4;

__device__ __forceinline__ bf16x8 ld8_b64(const __bf16* p) {
    union { unsigned long long q[2]; bf16x8 v; } u;
    u.q[0] = *reinterpret_cast<const unsigned long long*>(p);
    u.q[1] = *reinterpret_cast<const unsigned long long*>(p + 4);
    return u.v;
}

// async global->LDS, 16B per lane, dest = wave-uniform base + lane*16
__device__ __forceinline__ void gl16(const __bf16* g, __bf16* l) {
    __builtin_amdgcn_global_load_lds(
        (const __attribute__((address_space(1))) void*)g,
        (__attribute__((address_space(3))) void*)l, 16, 0, 0);
}

// ---------------- mega-prep: weight f2b + wpad + pf + head transpose + F0PRE zero + pimg ----------------
__global__ void prep_k(const float* __restrict__ proj_w, const float* __restrict__ Wqkv,
                       const float* __restrict__ Wo, const float* __restrict__ Wff1,
                       const float* __restrict__ Wff2,
                       __bf16* __restrict__ projWb, __bf16* __restrict__ WqkvB,
                       __bf16* __restrict__ WoB, __bf16* __restrict__ Wff1B,
                       __bf16* __restrict__ Wff2B,
                       const float* __restrict__ cw, __bf16* __restrict__ wpad,
                       const int* __restrict__ pos0, const int* __restrict__ pos1,
                       float* __restrict__ pf,
                       const float* __restrict__ rw1, const float* __restrict__ uw1,
                       float* __restrict__ rw1T, float* __restrict__ uw1T,
                       float* __restrict__ f0pre,
                       bfp __restrict__ img, __bf16* __restrict__ pimg)
{
    int i = blockIdx.x * 256 + threadIdx.x;
    if (i < 2328576) {
        const float* s; __bf16* d; int off;
        if      (i < 165888)  { s = proj_w; d = projWb; off = i; }
        else if (i < 608256)  { s = Wqkv;   d = WqkvB;  off = i - 165888; }
        else if (i < 755712)  { s = Wo;     d = WoB;    off = i - 608256; }
        else if (i < 1542144) { s = Wff1;   d = Wff1B;  off = i - 755712; }
        else                  { s = Wff2;   d = Wff2B;  off = i - 1542144; }
        float4 v = reinterpret_cast<const float4*>(s)[off];
        union { __bf16 h[4]; unsigned long long u; } p;
        p.h[0] = (__bf16)v.x; p.h[1] = (__bf16)v.y;
        p.h[2] = (__bf16)v.z; p.h[3] = (__bf16)v.w;
        reinterpret_cast<unsigned long long*>(d)[off] = p.u;
        return;
    }
    if (i < 2331648) {
        int e = i - 2328576;
        int r = e >> 5, g = e & 31;
        if (g >= 24) return;
        union { __bf16 h[8]; uint4 u; } w;
        #pragma unroll
        for (int kx = 0; kx < 8; ++kx) {
            float v = 0.f;
            if (g < 21 && kx < 7) v = cw[(size_t)r * 147 + g * 7 + kx];
            w.h[kx] = (__bf16)v;
        }
        *reinterpret_cast<uint4*>(&wpad[(size_t)r * 192 + g * 8]) = w.u;
        return;
    }
    if (i < 2332032) {
        int dd0 = i - 2331648;
        const float c1 = -logf(10000.f) / 128.f;
        for (int ss = 0; ss < 11; ++ss) {
            int py, px, pw;
            if (ss == 0) { py = pos0[0]; px = pos0[1]; pw = 0; }
            else { py = pos1[(ss - 1) * 2]; px = pos1[(ss - 1) * 2 + 1]; pw = 1; }
            float coordv; int dd = dd0;
            if (dd0 < 128) coordv = (float)(py - 64);
            else if (dd0 < 256) { coordv = (float)(px - 64); dd = dd0 - 128; }
            else { coordv = (pw == 0) ? 128.f : 24.f; dd = dd0 - 256; }
            int ii = dd >> 1;
            float div = expf((float)(2 * ii) * c1);
            float ang = coordv * div;
            pf[ss * 384 + dd0] = (dd & 1) ? cosf(ang) : sinf(ang);
        }
        return;
    }
    if (i < 2626944) {
        int e = i - 2332032;
        int which = e >= 147456;
        int t = which ? e - 147456 : e;
        int k = t / 384, dd = t - k * 384;
        if (which) uw1T[k * 384 + dd] = uw1[(size_t)dd * 384 + k];
        else       rw1T[k * 384 + dd] = rw1[(size_t)dd * 384 + k];
        return;
    }
    if (i < 2659712) {                  // F0PRE zero
        f0pre[i - 2626944] = 0.f;
        return;
    }
    if (i < 4484480) {                  // pimg window (uint4 chunks)
        int e = i - 2659712;
        int col8 = e % 18, t = e / 18;
        int row = t % 132; t /= 132;
        int ch = t % 3; int b = t / 3;
        int y = min(max(pos0[0], 0), 127), x = min(max(pos0[1], 0), 127);
        int y1 = max(0, y - 64), y2 = min(128, y + 64);
        int x1 = max(0, x - 64), x2 = min(128, x + 64);
        int iy = y1 + row - 1;
        bool rok = (row >= 1) && (iy < y2);
        const float* src = img + ((size_t)(b * 4 + ch) * 128 + iy) * 128;
        union { __bf16 h[8]; uint4 u; } p;
        #pragma unroll
        for (int k = 0; k < 8; ++k) {
            int cc = col8 * 8 + k;
            int ix = x1 + cc - 1;
            float v = 0.f;
            if (rok && cc >= 1 && ix < x2) v = src[ix];
            p.h[k] = (__bf16)v;
        }
        *reinterpret_cast<uint4*>(&pimg[((size_t)(b * 3 + ch) * 132 + row) * 144 + col8 * 8]) = p.u;
        return;
    }
}

// ---------------- win1 gather -> bf16 (AFTER convgemm: writes alias PIMG) ----------------
__global__ void win1_k(bfp __restrict__ img, const int* __restrict__ pos1,
                       __bf16* __restrict__ w1)
{
    int i = blockIdx.x * 256 + threadIdx.x;
    if (i >= B_ * 10 * 1728) return;
    int cc = i % 24, r = (i / 24) % 24, c = (i / 576) % 3, s = (i / 1728) % 10, b = i / 17280;
    int y = min(max(pos1[s * 2], 0), 127), x = min(max(pos1[s * 2 + 1], 0), 127);
    int y1 = max(0, y - 12), y2 = min(128, y + 12);
    int x1 = max(0, x - 12), x2 = min(128, x + 12);
    float v = 0.f;
    if ((y1 + r) < y2 && (x1 + cc) < x2)
        v = img[((size_t)(b * 4 + c) * 128 + (y1 + r)) * 128 + (x1 + cc)];
    w1[i] = (__bf16)v;
}

// ---------------- all-bf16 MFMA GEMM, BM=128 BN=64 BK=64, 3-stage counted-vmcnt pipeline ----------------
// Requires (kEnd-kStart)/64 >= 3 (all call sites: qkv 6, Wo 3, ff2 16, proj 14).
__global__ __launch_bounds__(256) void gemm_bb_k(
    const __bf16* __restrict__ A, const __bf16* __restrict__ W,
    const float* __restrict__ bias, const float* __restrict__ resid,
    void* __restrict__ C_, int M, int N, int K, int mode, int outBf16, int kChunk)
{
    __shared__ __align__(16) __bf16 AsF[3][8192];
    __shared__ __align__(16) __bf16 WsF[3][4096];
    const int tid = threadIdx.x;
    const int bm = blockIdx.y * 128, bn = blockIdx.x * 64;
    const int z = blockIdx.z;
    int kStart = 0, kEnd = K;
    if (kChunk) { kStart = z * kChunk; kEnd = min(K, kStart + kChunk); }
    const int lane = tid & 63, wv = tid >> 6;
    const int wrA = (wv >> 1) * 64, wcW = (wv & 1) * 32;
    const int lr = lane & 15, lk = lane >> 4;
    size_t gaoff[4], gwoff[2];
    #pragma unroll
    for (int k = 0; k < 4; ++k) {
        int c = tid + k * 256; int r = c >> 3; int j = (c & 7) ^ (r & 7);
        gaoff[k] = (size_t)(bm + r) * K + j * 8;
    }
    #pragma unroll
    for (int k = 0; k < 2; ++k) {
        int c = tid + k * 256; int r = c >> 3; int j = (c & 7) ^ (r & 7);
        gwoff[k] = (size_t)(bn + r) * K + j * 8;
    }
    f32x4 acc[4][2] = {};

#define STAGE3_(nb, kk) do {                                            \
        __bf16* bA = &AsF[nb][0]; __bf16* bW = &WsF[nb][0];             \
        gl16(A + gaoff[0] + (kk), bA + (wv << 9));                      \
        gl16(A + gaoff[1] + (kk), bA + 2048 + (wv << 9));               \
        gl16(A + gaoff[2] + (kk), bA + 4096 + (wv << 9));               \
        gl16(A + gaoff[3] + (kk), bA + 6144 + (wv << 9));               \
        gl16(W + gwoff[0] + (kk), bW + (wv << 9));                      \
        gl16(W + gwoff[1] + (kk), bW + 2048 + (wv << 9));               \
    } while (0)

    const int nIter = (kEnd - kStart) >> 6;
    STAGE3_(0, kStart);
    STAGE3_(1, kStart + 64);
    int cur = 0;
    for (int it = 0; it < nIter; ++it) {
        // oldest tile (it) resident; tile it+1's 6 loads stay in flight
        asm volatile("s_waitcnt vmcnt(6)" ::: "memory");
        __builtin_amdgcn_sched_barrier(0);
        asm volatile("s_waitcnt lgkmcnt(0)" ::: "memory");
        __builtin_amdgcn_s_barrier();
        // stage tile it+2 into buffer (cur+2)%3 (last read at iter it-1 -> safe)
        int nxt = it + 2; if (nxt >= nIter) nxt -= nIter;   // tail: dummy restage, never read
        int nb = cur + 2; if (nb >= 3) nb -= 3;
        STAGE3_(nb, kStart + nxt * 64);
        const __bf16* Ab = &AsF[cur][0];
        const __bf16* Wb = &WsF[cur][0];
        #pragma unroll
        for (int s = 0; s < 2; ++s) {
            int j = s * 4 + lk;
            int rw0 = wcW + lr, rw1_ = wcW + 16 + lr;
            bf16x8 w0 = *reinterpret_cast<const bf16x8*>(&Wb[rw0 * 64 + ((j ^ (rw0 & 7)) << 3)]);
            bf16x8 w1 = *reinterpret_cast<const bf16x8*>(&Wb[rw1_ * 64 + ((j ^ (rw1_ & 7)) << 3)]);
            #pragma unroll
            for (int m = 0; m < 4; ++m) {
                int ra = wrA + m * 16 + lr;
                bf16x8 a = *reinterpret_cast<const bf16x8*>(&Ab[ra * 64 + ((j ^ (ra & 7)) << 3)]);
                acc[m][0] = __builtin_amdgcn_mfma_f32_16x16x32_bf16(a, w0, acc[m][0], 0, 0, 0);
                acc[m][1] = __builtin_amdgcn_mfma_f32_16x16x32_bf16(a, w1, acc[m][1], 0, 0, 0);
            }
        }
        cur = cur + 1; if (cur == 3) cur = 0;
    }
#undef STAGE3_
    if (kChunk) {
        float* Cp = (float*)C_ + (size_t)z * M * N;
        #pragma unroll
        for (int m = 0; m < 4; ++m)
            #pragma unroll
            for (int n = 0; n < 2; ++n) {
                int col = bn + wcW + n * 16 + lr;
                #pragma unroll
                for (int i = 0; i < 4; ++i) {
                    int row = bm + wrA + m * 16 + lk * 4 + i;
                    Cp[(size_t)row * N + col] = acc[m][n][i];
                }
            }
    } else {
        #pragma unroll
        for (int m = 0; m < 4; ++m)
            #pragma unroll
            for (int n = 0; n < 2; ++n) {
                int col = bn + wcW + n * 16 + lr;
                float bcol = bias[col];
                #pragma unroll
                for (int i = 0; i < 4; ++i) {
                    int row = bm + wrA + m * 16 + lk * 4 + i;
                    float v = acc[m][n][i] + bcol;
                    if (mode == 1) v = fmaxf(v, 0.f);
                    if (mode == 2) v += resid[(size_t)row * N + col];
                    if (outBf16) ((__bf16*)C_)[(size_t)row * N + col] = (__bf16)v;
                    else         ((float*)C_)[(size_t)row * N + col] = v;
                }
            }
    }
}

// ---------------- BM=128 BN=128 BK=64 variant (ff1), 2-phase dbuf ----------------
__global__ __launch_bounds__(256) void gemm_bb128_k(
    const __bf16* __restrict__ A, const __bf16* __restrict__ W,
    const float* __restrict__ bias, void* __restrict__ C_,
    int M, int N, int K, int mode, int outBf16)
{
    __shared__ __align__(16) __bf16 AsF[2][8192];
    __shared__ __align__(16) __bf16 WsF[2][8192];
    const int tid = threadIdx.x;
    const int bm = blockIdx.y * 128, bn = blockIdx.x * 128;
    const int lane = tid & 63, wv = tid >> 6;
    const int wrA = (wv >> 1) * 64, wcW = (wv & 1) * 64;
    const int lr = lane & 15, lk = lane >> 4;
    size_t gaoff[4], gwoff[4];
    #pragma unroll
    for (int k = 0; k < 4; ++k) {
        int c = tid + k * 256; int r = c >> 3; int j = (c & 7) ^ (r & 7);
        gaoff[k] = (size_t)(bm + r) * K + j * 8;
        gwoff[k] = (size_t)(bn + r) * K + j * 8;
    }
    f32x4 acc[4][4] = {};

#define STAGE_(bf, kk) do {                                           \
        gl16(A + gaoff[0] + (kk), &AsF[bf][(wv << 9)]);               \
        gl16(A + gaoff[1] + (kk), &AsF[bf][2048 + (wv << 9)]);        \
        gl16(A + gaoff[2] + (kk), &AsF[bf][4096 + (wv << 9)]);        \
        gl16(A + gaoff[3] + (kk), &AsF[bf][6144 + (wv << 9)]);        \
        gl16(W + gwoff[0] + (kk), &WsF[bf][(wv << 9)]);               \
        gl16(W + gwoff[1] + (kk), &WsF[bf][2048 + (wv << 9)]);        \
        gl16(W + gwoff[2] + (kk), &WsF[bf][4096 + (wv << 9)]);        \
        gl16(W + gwoff[3] + (kk), &WsF[bf][6144 + (wv << 9)]);        \
    } while (0)

    STAGE_(0, 0);
    __syncthreads();
    int cur = 0;
    for (int k0 = 0; k0 < K; k0 += 64) {
        if (k0 + 64 < K) STAGE_(cur ^ 1, k0 + 64);
        const __bf16* Ab = AsF[cur];
        const __bf16* Wb = WsF[cur];
        #pragma unroll
        for (int s = 0; s < 2; ++s) {
            int j = s * 4 + lk;
            bf16x8 wfrag[4];
            #pragma unroll
            for (int n = 0; n < 4; ++n) {
                int rw = wcW + n * 16 + lr;
                wfrag[n] = *reinterpret_cast<const bf16x8*>(&Wb[rw * 64 + ((j ^ (rw & 7)) << 3)]);
            }
            #pragma unroll
            for (int m = 0; m < 4; ++m) {
                int ra = wrA + m * 16 + lr;
                bf16x8 a = *reinterpret_cast<const bf16x8*>(&Ab[ra * 64 + ((j ^ (ra & 7)) << 3)]);
                #pragma unroll
                for (int n = 0; n < 4; ++n)
                    acc[m][n] = __builtin_amdgcn_mfma_f32_16x16x32_bf16(a, wfrag[n], acc[m][n], 0, 0, 0);
            }
        }
        __syncthreads();
        cur ^= 1;
    }
#undef STAGE_
    #pragma unroll
    for (int m = 0; m < 4; ++m)
        #pragma unroll
        for (int n = 0; n < 4; ++n) {
            int col = bn + wcW + n * 16 + lr;
            float bcol = bias[col];
            #pragma unroll
            for (int i = 0; i < 4; ++i) {
                int row = bm + wrA + m * 16 + lk * 4 + i;
                float v = acc[m][n][i] + bcol;
                if (mode == 1) v = fmaxf(v, 0.f);
                if (outBf16) ((__bf16*)C_)[(size_t)row * N + col] = (__bf16)v;
                else         ((float*)C_)[(size_t)row * N + col] = v;
            }
        }
}

// ---------------- conv v5: gl16 patch staging from PIMG, 2-phase P dbuf ----------------
__global__ __launch_bounds__(256) void convgemm_k(
    const __bf16* __restrict__ pimg, const __bf16* __restrict__ wpad,
    bfp __restrict__ cb, float* __restrict__ f0pre)
{
    __shared__ __align__(16) __bf16 Wlds[64][200];
    __shared__ __align__(16) __bf16 P[2][4896];
    const int tid = threadIdx.x;
    const int blk = blockIdx.x;
    const int b = blk >> 3;
    const int bn = ((blk >> 2) & 1) * 64;
    const int mtg = blk & 3;
    const int lane = tid & 63, wv = tid >> 6;
    const int wr = (wv >> 1) * 32, wc = (wv & 1) * 32;
    const int lr = lane & 15, lk = lane >> 4;
    const int oyl = wr >> 5;
    const int ox0 = lr, ox1 = 16 + lr;

    size_t poff[3]; bool pval[3];
    #pragma unroll
    for (int p = 0; p < 3; ++p) {
        int c = tid + p * 256;
        pval[p] = (c < 612);
        int col8 = c % 17, rowi = c / 17;
        int r2 = rowi % 12, c3 = rowi / 12;
        poff[p] = ((size_t)(b * 3 + c3) * 132 + r2) * 144 + col8 * 8;
    }
#define STAGEP_(buf, mt) do {                                                 \
        if (pval[0]) gl16(pimg + poff[0] + (size_t)(mt) * 1152, &P[buf][(0 + (wv << 6)) * 8]);      \
        if (pval[1]) gl16(pimg + poff[1] + (size_t)(mt) * 1152, &P[buf][(256 + (wv << 6)) * 8]);    \
        if (pval[2]) gl16(pimg + poff[2] + (size_t)(mt) * 1152, &P[buf][(512 + (wv << 6)) * 8]);    \
    } while (0)

    STAGEP_(0, mtg * 4);
    for (int e = tid; e < 1536; e += 256) {
        int r = e / 24, g = e - r * 24;
        uint4 q = *reinterpret_cast<const uint4*>(&wpad[(size_t)(bn + r) * 192 + g * 8]);
        *reinterpret_cast<uint4*>(&Wlds[r][g * 8]) = q;
    }
    __syncthreads();

    float s0 = 0.f, s1 = 0.f;
    const float bc0 = cb[bn + wc + lr];
    const float bc1 = cb[bn + wc + 16 + lr];

    for (int t = 0; t < 4; ++t) {
        if (t < 3) STAGEP_((t + 1) & 1, mtg * 4 + t + 1);
        const __bf16* Pb = P[t & 1];
        f32x4 acc[2][2] = {};
        #pragma unroll
        for (int kk = 0; kk < 6; ++kk) {
            int g = kk * 4 + lk;
            int c = g / 7, ky = g - c * 7;
            if (g >= 21) { c = 0; ky = 0; }
            const __bf16* prow = &Pb[(c * 12 + oyl * 4 + ky) * 136];
            bf16x8 a0 = ld8_b64(prow + ox0 * 4);
            bf16x8 a1 = ld8_b64(prow + ox1 * 4);
            bf16x8 w0 = *reinterpret_cast<const bf16x8*>(&Wlds[wc + lr][g * 8]);
            bf16x8 w1 = *reinterpret_cast<const bf16x8*>(&Wlds[wc + 16 + lr][g * 8]);
            acc[0][0] = __builtin_amdgcn_mfma_f32_16x16x32_bf16(a0, w0, acc[0][0], 0, 0, 0);
            acc[0][1] = __builtin_amdgcn_mfma_f32_16x16x32_bf16(a0, w1, acc[0][1], 0, 0, 0);
            acc[1][0] = __builtin_amdgcn_mfma_f32_16x16x32_bf16(a1, w0, acc[1][0], 0, 0, 0);
            acc[1][1] = __builtin_amdgcn_mfma_f32_16x16x32_bf16(a1, w1, acc[1][1], 0, 0, 0);
        }
        #pragma unroll
        for (int m = 0; m < 2; ++m)
            #pragma unroll
            for (int i = 0; i < 4; ++i) {
                s0 += fmaxf(acc[m][0][i] + bc0, 0.f);
                s1 += fmaxf(acc[m][1][i] + bc1, 0.f);
            }
        __syncthreads();
    }
#undef STAGEP_
    s0 += __shfl_xor(s0, 16); s0 += __shfl_xor(s0, 32);
    s1 += __shfl_xor(s1, 16); s1 += __shfl_xor(s1, 32);
    if (lk == 0) {
        atomicAdd(&f0pre[b * 128 + bn + wc + lr],      s0 * (1.f / 1024.f));
        atomicAdd(&f0pre[b * 128 + bn + wc + 16 + lr], s1 * (1.f / 1024.f));
    }
}

// ---------------- x = feats + pf (f0 inline; f1 from 2 partials + bias) ----------------
__global__ void assemble_k(const float* __restrict__ f0pre, bfp __restrict__ ew,
                           bfp __restrict__ eb,
                           const float* __restrict__ p0, const float* __restrict__ p1,
                           const float* __restrict__ projb,
                           const float* __restrict__ pf, float* __restrict__ x,
                           __bf16* __restrict__ xb)
{
    int i = blockIdx.x * 256 + threadIdx.x;
    if (i >= B_ * S_ * D_) return;
    int d = i % 384, s = (i / 384) % 11, b = i / (384 * 11);
    float f;
    if (s == 0) {
        float acc = eb[d];
        const float* pre = f0pre + b * 128;
        const float* wrow = ew + (size_t)d * 128;
        #pragma unroll 4
        for (int co = 0; co < 128; ++co) acc += pre[co] * wrow[co];
        f = acc;
    } else {
        size_t o = ((size_t)(b * 10) + (s - 1)) * 384 + d;
        f = p0[o] + p1[o] + projb[d];
    }
    float v = f + pf[s * 384 + d];
    x[i] = v;
    xb[i] = (__bf16)v;
}

// ---------------- attention v2: one block per batch, all 12 heads ----------------
__global__ __launch_bounds__(256) void attn_k(const __bf16* __restrict__ qkv,
                                              __bf16* __restrict__ obuf)
{
    int b = blockIdx.x;
    __shared__ __bf16 qs[11][1160];
    __shared__ float att[12][11][11];
    const __bf16* src = qkv + (size_t)b * 11 * 1152;
    for (int c = threadIdx.x; c < 1584; c += 256) {
        int row = c / 144, col8 = c - row * 144;
        *reinterpret_cast<uint4*>(&qs[row][col8 * 8]) =
            *reinterpret_cast<const uint4*>(&src[c * 8]);
    }
    __syncthreads();
    for (int t = threadIdx.x; t < 1452; t += 256) {
        int h = t / 121, r = t - h * 121;
        int i = r / 11, j = r - i * 11;
        const __bf16* qp = &qs[i][h * 32];
        const __bf16* kp = &qs[j][384 + h * 32];
        float s = 0.f;
        #pragma unroll
        for (int d8 = 0; d8 < 4; ++d8) {
            bf16x8 qv = ld8_b64(qp + d8 * 8);
            bf16x8 kv = ld8_b64(kp + d8 * 8);
            #pragma unroll
            for (int e = 0; e < 8; ++e) s += (float)qv[e] * (float)kv[e];
        }
        att[h][i][j] = s * 0.17677669529663687f;
    }
    __syncthreads();
    for (int t = threadIdx.x; t < 132; t += 256) {
        int h = t / 11, i = t - h * 11;
        float mx = att[h][i][0];
        #pragma unroll
        for (int j = 1; j < 11; ++j) mx = fmaxf(mx, att[h][i][j]);
        float e_[11], sum = 0.f;
        #pragma unroll
        for (int j = 0; j < 11; ++j) { e_[j] = expf(att[h][i][j] - mx); sum += e_[j]; }
        float inv = 1.f / sum;
        #pragma unroll
        for (int j = 0; j < 11; ++j) att[h][i][j] = e_[j] * inv;
    }
    __syncthreads();
    for (int t = threadIdx.x; t < 4224; t += 256) {
        int i = t / 384, col = t - i * 384;
        int h = col >> 5;
        float s = 0.f;
        #pragma unroll
        for (int j = 0; j < 11; ++j) s += att[h][i][j] * (float)qs[j][768 + col];
        obuf[((size_t)b * 11 + i) * 384 + col] = (__bf16)s;
    }
}

// ---------------- layernorm over (sum of partials + resid + bias), wave per row ----------------
__global__ __launch_bounds__(512) void ln_k(const float* __restrict__ parts, int nparts,
                                            const float* __restrict__ resid,
                                            const float* __restrict__ bias,
                                            bfp g, bfp be, float* __restrict__ xo,
                                            __bf16* __restrict__ xb)
{
    int row = blockIdx.x * 8 + (threadIdx.x >> 6);
    int lane = threadIdx.x & 63;
    const size_t MN = (size_t)2816 * 384;
    float v[6];
    float s = 0.f, sq = 0.f;
    #pragma unroll
    for (int j = 0; j < 6; ++j) {
        int d = lane + 64 * j;
        size_t off = (size_t)row * 384 + d;
        float t = resid[off] + bias[d];
        for (int z = 0; z < nparts; ++z) t += parts[z * MN + off];
        v[j] = t; s += t; sq += t * t;
    }
    #pragma unroll
    for (int o = 32; o >= 1; o >>= 1) { s += __shfl_xor(s, o); sq += __shfl_xor(sq, o); }
    float mean = s * (1.f / 384.f);
    float var = sq * (1.f / 384.f) - mean * mean;
    float inv = rsqrtf(var + 1e-5f);
    float* xr = xo + (size_t)row * 384;
    __bf16* xbr = xb + (size_t)row * 384;
    #pragma unroll
    for (int j = 0; j < 6; ++j) {
        int d = lane + 64 * j;
        float o = (v[j] - mean) * inv * g[d] + be[d];
        xr[d] = o;
        xbr[d] = (__bf16)o;
    }
}

// ---------------- fused head v3: 768 threads, 2-way k-split phase 1 ----------------
__global__ __launch_bounds__(768) void headfused_k(
    const float* __restrict__ X,
    const float* __restrict__ rw1T, bfp __restrict__ rb1,
    const float* __restrict__ uw1T, bfp __restrict__ ub1,
    bfp __restrict__ rw2, bfp __restrict__ rb2, bfp __restrict__ uw2, bfp __restrict__ ub2,
    float* __restrict__ out)
{
    __shared__ float m[384], ph1[2][384], ph2[2][384], h1s[384], h2s[384];
    int b = blockIdx.x, t = threadIdx.x;
    int half = t / 384, d = t - half * 384;
    if (half == 0) {
        float s = 0.f;
        for (int si = 0; si < 11; ++si) s += X[((size_t)b * 11 + si) * 384 + d];
        m[d] = s * (1.f / 11.f);
    }
    __syncthreads();
    {
        float a1 = 0.f, a2 = 0.f;
        int k0 = half * 192;
        #pragma unroll 8
        for (int k = k0; k < k0 + 192; ++k) {
            float mk = m[k];
            a1 += mk * rw1T[k * 384 + d];
            a2 += mk * uw1T[k * 384 + d];
        }
        ph1[half][d] = a1;
        ph2[half][d] = a2;
    }
    __syncthreads();
    if (half == 0) {
        h1s[d] = fmaxf(ph1[0][d] + ph1[1][d] + rb1[d], 0.f);
        h2s[d] = fmaxf(ph2[0][d] + ph2[1][d] + ub1[d], 0.f);
    }
    __syncthreads();
    if (t < 64) {
        int lane = t;
        float acc[8] = {};
        for (int dd = lane; dd < 384; dd += 64) {
            float v1 = h1s[dd], v2 = h2s[dd];
            #pragma unroll
            for (int o = 0; o < 6; ++o) acc[o] += v1 * rw2[o * 384 + dd];
            acc[6] += v2 * uw2[dd];
            acc[7] += v2 * uw2[384 + dd];
        }
        #pragma unroll
        for (int o = 0; o < 8; ++o)
            #pragma unroll
            for (int off = 32; off >= 1; off >>= 1) acc[o] += __shfl_xor(acc[o], off);
        if (lane == 0) {
            float r[6];
            for (int o = 0; o < 6; ++o) r[o] = acc[o] + rb2[o];
            float u0 = acc[6] + ub2[0], u1 = acc[7] + ub2[1];
            float dot12 = r[0] * r[3] + r[1] * r[4] + r[2] * r[5];
            float q2x = r[3] - dot12 * r[0], q2y = r[4] - dot12 * r[1], q2z = r[5] - dot12 * r[2];
            float q3x = r[1] * q2z - r[2] * q2y;
            float q3y = r[2] * q2x - r[0] * q2z;
            float q3z = r[0] * q2y - r[1] * q2x;
            float n1 = fmaxf(sqrtf(r[0]*r[0] + r[1]*r[1] + r[2]*r[2]), 1e-12f);
            float n2 = fmaxf(sqrtf(q2x*q2x + q2y*q2y + q2z*q2z), 1e-12f);
            float n3 = fmaxf(sqrtf(q3x*q3x + q3y*q3y + q3z*q3z), 1e-12f);
            out[b * 2 + 0] = 1.f / (1.f + expf(-u0));
            out[b * 2 + 1] = 1.f / (1.f + expf(-u1));
            float* R = out + B_ * 2 + b * 9;
            R[0] = r[0] / n1; R[1] = r[1] / n1; R[2] = r[2] / n1;
            R[3] = q2x / n2;  R[4] = q2y / n2;  R[5] = q2z / n2;
            R[6] = q3x / n3;  R[7] = q3y / n3;  R[8] = q3z / n3;
        }
    }
}

extern "C" void kernel_launch(void* const* d_in, const int* in_sizes, int n_in,
                              void* d_out, int out_size, void* d_ws, size_t ws_size,
                              hipStream_t stream)
{
    bfp rgb     = (bfp)d_in[0];
    const int* pos0 = (const int*)d_in[1];
    const int* pos1 = (const int*)d_in[2];
    bfp conv_w  = (bfp)d_in[3];
    bfp conv_b  = (bfp)d_in[4];
    bfp ext_w   = (bfp)d_in[5];
    bfp ext_b   = (bfp)d_in[6];
    bfp proj_w  = (bfp)d_in[7];
    bfp proj_b  = (bfp)d_in[8];
    bfp Wqkv    = (bfp)d_in[9];
    bfp bqkv    = (bfp)d_in[10];
    bfp Wo      = (bfp)d_in[11];
    bfp bo      = (bfp)d_in[12];
    bfp ln1g    = (bfp)d_in[13];
    bfp ln1b    = (bfp)d_in[14];
    bfp ln2g    = (bfp)d_in[15];
    bfp ln2b    = (bfp)d_in[16];
    bfp Wff1    = (bfp)d_in[17];
    bfp bff1    = (bfp)d_in[18];
    bfp Wff2    = (bfp)d_in[19];
    bfp bff2    = (bfp)d_in[20];
    bfp rw1     = (bfp)d_in[21];
    bfp rb1     = (bfp)d_in[22];
    bfp rw2     = (bfp)d_in[23];
    bfp rb2     = (bfp)d_in[24];
    bfp uw1     = (bfp)d_in[25];
    bfp ub1     = (bfp)d_in[26];
    bfp uw2     = (bfp)d_in[27];
    bfp ub2     = (bfp)d_in[28];

    float* ws = (float*)d_ws;
    float*  X      = ws;
    __bf16* PIMG   = (__bf16*)(ws + 1081344);
    float*  QKV    = ws + 2162688;
    __bf16* QKVb   = (__bf16*)QKV;
    float*  PP0    = ws + 3276800;
    float*  PP1    = ws + 4259840;
    __bf16* OBUFb  = (__bf16*)(ws + 5406720);
    __bf16* FFH16  = (__bf16*)(ws + 6144000);
    __bf16* WIN1F16= FFH16;
    float*  PF     = ws + 9027584;
    float*  F0PRE  = ws + 9031808;
    __bf16* Xb     = (__bf16*)(ws + 9130112);
    __bf16* projWb = (__bf16*)(ws + 9670784);
    __bf16* WqkvB  = (__bf16*)(ws + 10002560);
    __bf16* WoB    = (__bf16*)(ws + 10887296);
    __bf16* Wff1B  = (__bf16*)(ws + 11182208);
    __bf16* Wff2B  = (__bf16*)(ws + 12755072);
    __bf16* WpadC  = (__bf16*)(ws + 14327936);
    float*  RW1T   = ws + 14340224;
    float*  UW1T   = ws + 14487680;

    prep_k<<<17518, 256, 0, stream>>>(proj_w, Wqkv, Wo, Wff1, Wff2,
                                      projWb, WqkvB, WoB, Wff1B, Wff2B,
                                      conv_w, WpadC, pos0, pos1, PF,
                                      rw1, uw1, RW1T, UW1T,
                                      F0PRE, rgb, PIMG);
    convgemm_k<<<2048, 256, 0, stream>>>(PIMG, WpadC, conv_b, F0PRE);
    win1_k<<<(B_ * 10 * 1728 + 255) / 256, 256, 0, stream>>>(rgb, pos1, WIN1F16);
    gemm_bb_k<<<dim3(6, 20, 2), 256, 0, stream>>>(WIN1F16, projWb, nullptr, nullptr,
                                                  PP0, 2560, 384, 1728, 0, 0, 896);
    assemble_k<<<(B_ * S_ * D_ + 255) / 256, 256, 0, stream>>>(
        F0PRE, ext_w, ext_b, PP0, PP1, proj_b, PF, X, Xb);

    for (int i = 0; i < 4; ++i) {
        gemm_bb_k<<<dim3(18, 22), 256, 0, stream>>>(
            Xb, WqkvB + (size_t)i * 1152 * 384, bqkv + i * 1152, nullptr, QKVb,
            2816, 1152, 384, 0, 1, 0);
        attn_k<<<B_, 256, 0, stream>>>(QKVb, OBUFb);
        gemm_bb_k<<<dim3(6, 22, 2), 256, 0, stream>>>(
            OBUFb, WoB + (size_t)i * 384 * 384, nullptr, nullptr, QKV,
            2816, 384, 384, 0, 0, 192);
        ln_k<<<352, 512, 0, stream>>>(QKV, 2, X, bo + i * 384,
                                      ln1g + i * 384, ln1b + i * 384, X, Xb);
        gemm_bb128_k<<<dim3(16, 22), 256, 0, stream>>>(
            Xb, Wff1B + (size_t)i * 2048 * 384, bff1 + i * 2048, FFH16,
            2816, 2048, 384, 1, 1);
        gemm_bb_k<<<dim3(6, 22, 2), 256, 0, stream>>>(
            FFH16, Wff2B + (size_t)i * 384 * 2048, nullptr, nullptr, QKV,
            2816, 384, 2048, 0, 0, 1024);
        ln_k<<<352, 512, 0, stream>>>(QKV, 2, X, bff2 + i * 384,
                                      ln2g + i * 384, ln2b + i * 384, X, Xb);
    }

    headfused_k<<<256, 768, 0, stream>>>(X, RW1T, rb1, UW1T, ub1,
                                         rw2, rb2, uw2, ub2, (float*)d_out);
}

// Round 19
// 425.652 us; speedup vs baseline: 1.0852x; 1.0852x over previous
//
#include <hip/hip_runtime.h>
#include <hip/hip_bf16.h>

#define B_ 256
#define S_ 11
#define D_ 384
#define NHEAD_ 12

typedef const float* bfp;
typedef __attribute__((ext_vector_type(8))) __bf16 bf16x8;
typedef __attribute__((ext_vector_type(4))) float f32x4;

__device__ __forceinline__ bf16x8 ld8_b64(const __bf16* p) {
    union { unsigned long long q[2]; bf16x8 v; } u;
    u.q[0] = *reinterpret_cast<const unsigned long long*>(p);
    u.q[1] = *reinterpret_cast<const unsigned long long*>(p + 4);
    return u.v;
}

// async global->LDS, 16B per lane, dest = wave-uniform base + lane*16
__device__ __forceinline__ void gl16(const __bf16* g, __bf16* l) {
    __builtin_amdgcn_global_load_lds(
        (const __attribute__((address_space(1))) void*)g,
        (__attribute__((address_space(3))) void*)l, 16, 0, 0);
}

// ---------------- fused prep: weight f2b + conv wpad + pf + head-weight transpose ----------------
__global__ void prep_k(const float* __restrict__ proj_w, const float* __restrict__ Wqkv,
                       const float* __restrict__ Wo, const float* __restrict__ Wff1,
                       const float* __restrict__ Wff2,
                       __bf16* __restrict__ projWb, __bf16* __restrict__ WqkvB,
                       __bf16* __restrict__ WoB, __bf16* __restrict__ Wff1B,
                       __bf16* __restrict__ Wff2B,
                       const float* __restrict__ cw, __bf16* __restrict__ wpad,
                       const int* __restrict__ pos0, const int* __restrict__ pos1,
                       float* __restrict__ pf,
                       const float* __restrict__ rw1, const float* __restrict__ uw1,
                       float* __restrict__ rw1T, float* __restrict__ uw1T)
{
    int i = blockIdx.x * 256 + threadIdx.x;
    const float* s; __bf16* d; int off;
    if      (i < 165888)  { s = proj_w; d = projWb; off = i; }
    else if (i < 608256)  { s = Wqkv;   d = WqkvB;  off = i - 165888; }
    else if (i < 755712)  { s = Wo;     d = WoB;    off = i - 608256; }
    else if (i < 1542144) { s = Wff1;   d = Wff1B;  off = i - 755712; }
    else if (i < 2328576) { s = Wff2;   d = Wff2B;  off = i - 1542144; }
    else if (i < 2331648) {
        int e = i - 2328576;
        int r = e >> 5, g = e & 31;
        if (g >= 24) return;
        union { __bf16 h[8]; uint4 u; } w;
        #pragma unroll
        for (int kx = 0; kx < 8; ++kx) {
            float v = 0.f;
            if (g < 21 && kx < 7) v = cw[(size_t)r * 147 + g * 7 + kx];
            w.h[kx] = (__bf16)v;
        }
        *reinterpret_cast<uint4*>(&wpad[(size_t)r * 192 + g * 8]) = w.u;
        return;
    }
    else if (i < 2332032) {
        int dd0 = i - 2331648;
        const float c1 = -logf(10000.f) / 128.f;
        for (int ss = 0; ss < 11; ++ss) {
            int py, px, pw;
            if (ss == 0) { py = pos0[0]; px = pos0[1]; pw = 0; }
            else { py = pos1[(ss - 1) * 2]; px = pos1[(ss - 1) * 2 + 1]; pw = 1; }
            float coordv; int dd = dd0;
            if (dd0 < 128) coordv = (float)(py - 64);
            else if (dd0 < 256) { coordv = (float)(px - 64); dd = dd0 - 128; }
            else { coordv = (pw == 0) ? 128.f : 24.f; dd = dd0 - 256; }
            int ii = dd >> 1;
            float div = expf((float)(2 * ii) * c1);
            float ang = coordv * div;
            pf[ss * 384 + dd0] = (dd & 1) ? cosf(ang) : sinf(ang);
        }
        return;
    }
    else if (i < 2626944) {
        int e = i - 2332032;
        int which = e >= 147456;
        int t = which ? e - 147456 : e;
        int k = t / 384, dd = t - k * 384;
        if (which) uw1T[k * 384 + dd] = uw1[(size_t)dd * 384 + k];
        else       rw1T[k * 384 + dd] = rw1[(size_t)dd * 384 + k];
        return;
    }
    else return;
    float4 v = reinterpret_cast<const float4*>(s)[off];
    union { __bf16 h[4]; unsigned long long u; } p;
    p.h[0] = (__bf16)v.x; p.h[1] = (__bf16)v.y;
    p.h[2] = (__bf16)v.z; p.h[3] = (__bf16)v.w;
    reinterpret_cast<unsigned long long*>(d)[off] = p.u;
}

// ---------------- masked padded win0 image: PIMG[b][c][132][144] bf16 ----------------
__global__ void pimg_k(bfp __restrict__ img, const int* __restrict__ pos0,
                       __bf16* __restrict__ pimg)
{
    int i = blockIdx.x * 256 + threadIdx.x;
    if (i >= 1824768) return;
    int col8 = i % 18, t = i / 18;
    int row = t % 132; t /= 132;
    int ch = t % 3; int b = t / 3;
    int y = min(max(pos0[0], 0), 127), x = min(max(pos0[1], 0), 127);
    int y1 = max(0, y - 64), y2 = min(128, y + 64);
    int x1 = max(0, x - 64), x2 = min(128, x + 64);
    int iy = y1 + row - 1;
    bool rok = (row >= 1) && (iy < y2);
    const float* src = img + ((size_t)(b * 4 + ch) * 128 + iy) * 128;
    union { __bf16 h[8]; uint4 u; } p;
    #pragma unroll
    for (int k = 0; k < 8; ++k) {
        int cc = col8 * 8 + k;
        int ix = x1 + cc - 1;
        float v = 0.f;
        if (rok && cc >= 1 && ix < x2) v = src[ix];
        p.h[k] = (__bf16)v;
    }
    *reinterpret_cast<uint4*>(&pimg[((size_t)(b * 3 + ch) * 132 + row) * 144 + col8 * 8]) = p.u;
}

// ---------------- all-bf16 MFMA GEMM, BM=128 BN=64 BK=64, 2-phase dbuf gl16 ----------------
__global__ __launch_bounds__(256) void gemm_bb_k(
    const __bf16* __restrict__ A, const __bf16* __restrict__ W,
    const float* __restrict__ bias, const float* __restrict__ resid,
    void* __restrict__ C_, int M, int N, int K, int mode, int outBf16, int kChunk)
{
    __shared__ __align__(16) __bf16 AsF[2][8192];
    __shared__ __align__(16) __bf16 WsF[2][4096];
    const int tid = threadIdx.x;
    const int bm = blockIdx.y * 128, bn = blockIdx.x * 64;
    const int z = blockIdx.z;
    int kStart = 0, kEnd = K;
    if (kChunk) { kStart = z * kChunk; kEnd = min(K, kStart + kChunk); }
    const int lane = tid & 63, wv = tid >> 6;
    const int wrA = (wv >> 1) * 64, wcW = (wv & 1) * 32;
    const int lr = lane & 15, lk = lane >> 4;
    size_t gaoff[4], gwoff[2];
    #pragma unroll
    for (int k = 0; k < 4; ++k) {
        int c = tid + k * 256; int r = c >> 3; int j = (c & 7) ^ (r & 7);
        gaoff[k] = (size_t)(bm + r) * K + j * 8;
    }
    #pragma unroll
    for (int k = 0; k < 2; ++k) {
        int c = tid + k * 256; int r = c >> 3; int j = (c & 7) ^ (r & 7);
        gwoff[k] = (size_t)(bn + r) * K + j * 8;
    }
    f32x4 acc[4][2] = {};

#define STAGE_(bf, kk) do {                                       \
        gl16(A + gaoff[0] + (kk), &AsF[bf][(wv << 9)]);           \
        gl16(A + gaoff[1] + (kk), &AsF[bf][2048 + (wv << 9)]);    \
        gl16(A + gaoff[2] + (kk), &AsF[bf][4096 + (wv << 9)]);    \
        gl16(A + gaoff[3] + (kk), &AsF[bf][6144 + (wv << 9)]);    \
        gl16(W + gwoff[0] + (kk), &WsF[bf][(wv << 9)]);           \
        gl16(W + gwoff[1] + (kk), &WsF[bf][2048 + (wv << 9)]);    \
    } while (0)

    STAGE_(0, kStart);
    __syncthreads();
    int cur = 0;
    for (int k0 = kStart; k0 < kEnd; k0 += 64) {
        if (k0 + 64 < kEnd) STAGE_(cur ^ 1, k0 + 64);
        const __bf16* Ab = AsF[cur];
        const __bf16* Wb = WsF[cur];
        #pragma unroll
        for (int s = 0; s < 2; ++s) {
            int j = s * 4 + lk;
            int rw0 = wcW + lr, rw1_ = wcW + 16 + lr;
            bf16x8 w0 = *reinterpret_cast<const bf16x8*>(&Wb[rw0 * 64 + ((j ^ (rw0 & 7)) << 3)]);
            bf16x8 w1 = *reinterpret_cast<const bf16x8*>(&Wb[rw1_ * 64 + ((j ^ (rw1_ & 7)) << 3)]);
            #pragma unroll
            for (int m = 0; m < 4; ++m) {
                int ra = wrA + m * 16 + lr;
                bf16x8 a = *reinterpret_cast<const bf16x8*>(&Ab[ra * 64 + ((j ^ (ra & 7)) << 3)]);
                acc[m][0] = __builtin_amdgcn_mfma_f32_16x16x32_bf16(a, w0, acc[m][0], 0, 0, 0);
                acc[m][1] = __builtin_amdgcn_mfma_f32_16x16x32_bf16(a, w1, acc[m][1], 0, 0, 0);
            }
        }
        __syncthreads();
        cur ^= 1;
    }
#undef STAGE_
    if (kChunk) {
        float* Cp = (float*)C_ + (size_t)z * M * N;
        #pragma unroll
        for (int m = 0; m < 4; ++m)
            #pragma unroll
            for (int n = 0; n < 2; ++n) {
                int col = bn + wcW + n * 16 + lr;
                #pragma unroll
                for (int i = 0; i < 4; ++i) {
                    int row = bm + wrA + m * 16 + lk * 4 + i;
                    Cp[(size_t)row * N + col] = acc[m][n][i];
                }
            }
    } else {
        #pragma unroll
        for (int m = 0; m < 4; ++m)
            #pragma unroll
            for (int n = 0; n < 2; ++n) {
                int col = bn + wcW + n * 16 + lr;
                float bcol = bias[col];
                #pragma unroll
                for (int i = 0; i < 4; ++i) {
                    int row = bm + wrA + m * 16 + lk * 4 + i;
                    float v = acc[m][n][i] + bcol;
                    if (mode == 1) v = fmaxf(v, 0.f);
                    if (mode == 2) v += resid[(size_t)row * N + col];
                    if (outBf16) ((__bf16*)C_)[(size_t)row * N + col] = (__bf16)v;
                    else         ((float*)C_)[(size_t)row * N + col] = v;
                }
            }
    }
}

// ---------------- BM=128 BN=128 BK=64 variant (ff1: N=2048) ----------------
__global__ __launch_bounds__(256) void gemm_bb128_k(
    const __bf16* __restrict__ A, const __bf16* __restrict__ W,
    const float* __restrict__ bias, void* __restrict__ C_,
    int M, int N, int K, int mode, int outBf16)
{
    __shared__ __align__(16) __bf16 AsF[2][8192];
    __shared__ __align__(16) __bf16 WsF[2][8192];
    const int tid = threadIdx.x;
    const int bm = blockIdx.y * 128, bn = blockIdx.x * 128;
    const int lane = tid & 63, wv = tid >> 6;
    const int wrA = (wv >> 1) * 64, wcW = (wv & 1) * 64;
    const int lr = lane & 15, lk = lane >> 4;
    size_t gaoff[4], gwoff[4];
    #pragma unroll
    for (int k = 0; k < 4; ++k) {
        int c = tid + k * 256; int r = c >> 3; int j = (c & 7) ^ (r & 7);
        gaoff[k] = (size_t)(bm + r) * K + j * 8;
        gwoff[k] = (size_t)(bn + r) * K + j * 8;
    }
    f32x4 acc[4][4] = {};

#define STAGE_(bf, kk) do {                                           \
        gl16(A + gaoff[0] + (kk), &AsF[bf][(wv << 9)]);               \
        gl16(A + gaoff[1] + (kk), &AsF[bf][2048 + (wv << 9)]);        \
        gl16(A + gaoff[2] + (kk), &AsF[bf][4096 + (wv << 9)]);        \
        gl16(A + gaoff[3] + (kk), &AsF[bf][6144 + (wv << 9)]);        \
        gl16(W + gwoff[0] + (kk), &WsF[bf][(wv << 9)]);               \
        gl16(W + gwoff[1] + (kk), &WsF[bf][2048 + (wv << 9)]);        \
        gl16(W + gwoff[2] + (kk), &WsF[bf][4096 + (wv << 9)]);        \
        gl16(W + gwoff[3] + (kk), &WsF[bf][6144 + (wv << 9)]);        \
    } while (0)

    STAGE_(0, 0);
    __syncthreads();
    int cur = 0;
    for (int k0 = 0; k0 < K; k0 += 64) {
        if (k0 + 64 < K) STAGE_(cur ^ 1, k0 + 64);
        const __bf16* Ab = AsF[cur];
        const __bf16* Wb = WsF[cur];
        #pragma unroll
        for (int s = 0; s < 2; ++s) {
            int j = s * 4 + lk;
            bf16x8 wfrag[4];
            #pragma unroll
            for (int n = 0; n < 4; ++n) {
                int rw = wcW + n * 16 + lr;
                wfrag[n] = *reinterpret_cast<const bf16x8*>(&Wb[rw * 64 + ((j ^ (rw & 7)) << 3)]);
            }
            #pragma unroll
            for (int m = 0; m < 4; ++m) {
                int ra = wrA + m * 16 + lr;
                bf16x8 a = *reinterpret_cast<const bf16x8*>(&Ab[ra * 64 + ((j ^ (ra & 7)) << 3)]);
                #pragma unroll
                for (int n = 0; n < 4; ++n)
                    acc[m][n] = __builtin_amdgcn_mfma_f32_16x16x32_bf16(a, wfrag[n], acc[m][n], 0, 0, 0);
            }
        }
        __syncthreads();
        cur ^= 1;
    }
#undef STAGE_
    #pragma unroll
    for (int m = 0; m < 4; ++m)
        #pragma unroll
        for (int n = 0; n < 4; ++n) {
            int col = bn + wcW + n * 16 + lr;
            float bcol = bias[col];
            #pragma unroll
            for (int i = 0; i < 4; ++i) {
                int row = bm + wrA + m * 16 + lk * 4 + i;
                float v = acc[m][n][i] + bcol;
                if (mode == 1) v = fmaxf(v, 0.f);
                if (outBf16) ((__bf16*)C_)[(size_t)row * N + col] = (__bf16)v;
                else         ((float*)C_)[(size_t)row * N + col] = v;
            }
        }
}

// ---------------- conv v5: gl16 patch staging from PIMG, 2-phase P dbuf ----------------
__global__ __launch_bounds__(256) void convgemm_k(
    const __bf16* __restrict__ pimg, const __bf16* __restrict__ wpad,
    bfp __restrict__ cb, float* __restrict__ f0pre)
{
    __shared__ __align__(16) __bf16 Wlds[64][200];
    __shared__ __align__(16) __bf16 P[2][4896];
    const int tid = threadIdx.x;
    const int blk = blockIdx.x;
    const int b = blk >> 3;
    const int bn = ((blk >> 2) & 1) * 64;
    const int mtg = blk & 3;
    const int lane = tid & 63, wv = tid >> 6;
    const int wr = (wv >> 1) * 32, wc = (wv & 1) * 32;
    const int lr = lane & 15, lk = lane >> 4;
    const int oyl = wr >> 5;
    const int ox0 = lr, ox1 = 16 + lr;

    size_t poff[3]; bool pval[3];
    #pragma unroll
    for (int p = 0; p < 3; ++p) {
        int c = tid + p * 256;
        pval[p] = (c < 612);
        int col8 = c % 17, rowi = c / 17;
        int r2 = rowi % 12, c3 = rowi / 12;
        poff[p] = ((size_t)(b * 3 + c3) * 132 + r2) * 144 + col8 * 8;
    }
#define STAGEP_(buf, mt) do {                                                 \
        if (pval[0]) gl16(pimg + poff[0] + (size_t)(mt) * 1152, &P[buf][(0 + (wv << 6)) * 8]);      \
        if (pval[1]) gl16(pimg + poff[1] + (size_t)(mt) * 1152, &P[buf][(256 + (wv << 6)) * 8]);    \
        if (pval[2]) gl16(pimg + poff[2] + (size_t)(mt) * 1152, &P[buf][(512 + (wv << 6)) * 8]);    \
    } while (0)

    STAGEP_(0, mtg * 4);
    for (int e = tid; e < 1536; e += 256) {
        int r = e / 24, g = e - r * 24;
        uint4 q = *reinterpret_cast<const uint4*>(&wpad[(size_t)(bn + r) * 192 + g * 8]);
        *reinterpret_cast<uint4*>(&Wlds[r][g * 8]) = q;
    }
    __syncthreads();

    float s0 = 0.f, s1 = 0.f;
    const float bc0 = cb[bn + wc + lr];
    const float bc1 = cb[bn + wc + 16 + lr];

    for (int t = 0; t < 4; ++t) {
        if (t < 3) STAGEP_((t + 1) & 1, mtg * 4 + t + 1);
        const __bf16* Pb = P[t & 1];
        f32x4 acc[2][2] = {};
        #pragma unroll
        for (int kk = 0; kk < 6; ++kk) {
            int g = kk * 4 + lk;
            int c = g / 7, ky = g - c * 7;
            if (g >= 21) { c = 0; ky = 0; }
            const __bf16* prow = &Pb[(c * 12 + oyl * 4 + ky) * 136];
            bf16x8 a0 = ld8_b64(prow + ox0 * 4);
            bf16x8 a1 = ld8_b64(prow + ox1 * 4);
            bf16x8 w0 = *reinterpret_cast<const bf16x8*>(&Wlds[wc + lr][g * 8]);
            bf16x8 w1 = *reinterpret_cast<const bf16x8*>(&Wlds[wc + 16 + lr][g * 8]);
            acc[0][0] = __builtin_amdgcn_mfma_f32_16x16x32_bf16(a0, w0, acc[0][0], 0, 0, 0);
            acc[0][1] = __builtin_amdgcn_mfma_f32_16x16x32_bf16(a0, w1, acc[0][1], 0, 0, 0);
            acc[1][0] = __builtin_amdgcn_mfma_f32_16x16x32_bf16(a1, w0, acc[1][0], 0, 0, 0);
            acc[1][1] = __builtin_amdgcn_mfma_f32_16x16x32_bf16(a1, w1, acc[1][1], 0, 0, 0);
        }
        #pragma unroll
        for (int m = 0; m < 2; ++m)
            #pragma unroll
            for (int i = 0; i < 4; ++i) {
                s0 += fmaxf(acc[m][0][i] + bc0, 0.f);
                s1 += fmaxf(acc[m][1][i] + bc1, 0.f);
            }
        __syncthreads();
    }
#undef STAGEP_
    s0 += __shfl_xor(s0, 16); s0 += __shfl_xor(s0, 32);
    s1 += __shfl_xor(s1, 16); s1 += __shfl_xor(s1, 32);
    if (lk == 0) {
        atomicAdd(&f0pre[b * 128 + bn + wc + lr],      s0 * (1.f / 1024.f));
        atomicAdd(&f0pre[b * 128 + bn + wc + 16 + lr], s1 * (1.f / 1024.f));
    }
}

// ---------------- win1 gather -> bf16 ----------------
__global__ void win1_k(bfp __restrict__ img, const int* __restrict__ pos1,
                       __bf16* __restrict__ w1)
{
    int i = blockIdx.x * 256 + threadIdx.x;
    if (i >= B_ * 10 * 1728) return;
    int cc = i % 24, r = (i / 24) % 24, c = (i / 576) % 3, s = (i / 1728) % 10, b = i / 17280;
    int y = min(max(pos1[s * 2], 0), 127), x = min(max(pos1[s * 2 + 1], 0), 127);
    int y1 = max(0, y - 12), y2 = min(128, y + 12);
    int x1 = max(0, x - 12), x2 = min(128, x + 12);
    float v = 0.f;
    if ((y1 + r) < y2 && (x1 + cc) < x2)
        v = img[((size_t)(b * 4 + c) * 128 + (y1 + r)) * 128 + (x1 + cc)];
    w1[i] = (__bf16)v;
}

// ---------------- x = feats + pf (f0 inline; f1 from 2 partials + bias) ----------------
__global__ void assemble_k(const float* __restrict__ f0pre, bfp __restrict__ ew,
                           bfp __restrict__ eb,
                           const float* __restrict__ p0, const float* __restrict__ p1,
                           const float* __restrict__ projb,
                           const float* __restrict__ pf, float* __restrict__ x,
                           __bf16* __restrict__ xb)
{
    int i = blockIdx.x * 256 + threadIdx.x;
    if (i >= B_ * S_ * D_) return;
    int d = i % 384, s = (i / 384) % 11, b = i / (384 * 11);
    float f;
    if (s == 0) {
        float acc = eb[d];
        const float* pre = f0pre + b * 128;
        const float* wrow = ew + (size_t)d * 128;
        #pragma unroll 4
        for (int co = 0; co < 128; ++co) acc += pre[co] * wrow[co];
        f = acc;
    } else {
        size_t o = ((size_t)(b * 10) + (s - 1)) * 384 + d;
        f = p0[o] + p1[o] + projb[d];
    }
    float v = f + pf[s * 384 + d];
    x[i] = v;
    xb[i] = (__bf16)v;
}

// ---------------- attention per (b, head); qkv bf16 in, out bf16 ----------------
__global__ __launch_bounds__(128) void attn_k(const __bf16* __restrict__ qkv,
                                              __bf16* __restrict__ obuf)
{
    int b = blockIdx.x / NHEAD_, h = blockIdx.x % NHEAD_;
    __shared__ float q[11][32], k[11][32], v[11][32], att[11][12];
    for (int e = threadIdx.x; e < 352; e += 128) {
        int s = e >> 5, d = e & 31;
        size_t base = (size_t)(b * 11 + s) * 1152 + h * 32 + d;
        q[s][d] = (float)qkv[base];
        k[s][d] = (float)qkv[base + 384];
        v[s][d] = (float)qkv[base + 768];
    }
    __syncthreads();
    if (threadIdx.x < 121) {
        int i = threadIdx.x / 11, j = threadIdx.x % 11;
        float s = 0.f;
        #pragma unroll
        for (int d = 0; d < 32; ++d) s += q[i][d] * k[j][d];
        att[i][j] = s * 0.17677669529663687f;
    }
    __syncthreads();
    if (threadIdx.x < 11) {
        int i = threadIdx.x;
        float mx = att[i][0];
        for (int j = 1; j < 11; ++j) mx = fmaxf(mx, att[i][j]);
        float e_[11], sum = 0.f;
        for (int j = 0; j < 11; ++j) { e_[j] = expf(att[i][j] - mx); sum += e_[j]; }
        float inv = 1.f / sum;
        for (int j = 0; j < 11; ++j) att[i][j] = e_[j] * inv;
    }
    __syncthreads();
    for (int e = threadIdx.x; e < 352; e += 128) {
        int i = e >> 5, d = e & 31;
        float s = 0.f;
        #pragma unroll
        for (int j = 0; j < 11; ++j) s += att[i][j] * v[j][d];
        obuf[(size_t)(b * 11 + i) * 384 + h * 32 + d] = (__bf16)s;
    }
}

// ---------------- layernorm over (sum of partials + resid + bias), wave per row ----------------
__global__ __launch_bounds__(512) void ln_k(const float* __restrict__ parts, int nparts,
                                            const float* __restrict__ resid,
                                            const float* __restrict__ bias,
                                            bfp g, bfp be, float* __restrict__ xo,
                                            __bf16* __restrict__ xb)
{
    int row = blockIdx.x * 8 + (threadIdx.x >> 6);
    int lane = threadIdx.x & 63;
    const size_t MN = (size_t)2816 * 384;
    float v[6];
    float s = 0.f, sq = 0.f;
    #pragma unroll
    for (int j = 0; j < 6; ++j) {
        int d = lane + 64 * j;
        size_t off = (size_t)row * 384 + d;
        float t = resid[off] + bias[d];
        for (int z = 0; z < nparts; ++z) t += parts[z * MN + off];
        v[j] = t; s += t; sq += t * t;
    }
    #pragma unroll
    for (int o = 32; o >= 1; o >>= 1) { s += __shfl_xor(s, o); sq += __shfl_xor(sq, o); }
    float mean = s * (1.f / 384.f);
    float var = sq * (1.f / 384.f) - mean * mean;
    float inv = rsqrtf(var + 1e-5f);
    float* xr = xo + (size_t)row * 384;
    __bf16* xbr = xb + (size_t)row * 384;
    #pragma unroll
    for (int j = 0; j < 6; ++j) {
        int d = lane + 64 * j;
        float o = (v[j] - mean) * inv * g[d] + be[d];
        xr[d] = o;
        xbr[d] = (__bf16)o;
    }
}

// ---------------- fused head v3: 768 threads, 2-way k-split phase 1 ----------------
__global__ __launch_bounds__(768) void headfused_k(
    const float* __restrict__ X,
    const float* __restrict__ rw1T, bfp __restrict__ rb1,
    const float* __restrict__ uw1T, bfp __restrict__ ub1,
    bfp __restrict__ rw2, bfp __restrict__ rb2, bfp __restrict__ uw2, bfp __restrict__ ub2,
    float* __restrict__ out)
{
    __shared__ float m[384], ph1[2][384], ph2[2][384], h1s[384], h2s[384];
    int b = blockIdx.x, t = threadIdx.x;
    int half = t / 384, d = t - half * 384;
    if (half == 0) {
        float s = 0.f;
        for (int si = 0; si < 11; ++si) s += X[((size_t)b * 11 + si) * 384 + d];
        m[d] = s * (1.f / 11.f);
    }
    __syncthreads();
    {
        float a1 = 0.f, a2 = 0.f;
        int k0 = half * 192;
        #pragma unroll 8
        for (int k = k0; k < k0 + 192; ++k) {
            float mk = m[k];
            a1 += mk * rw1T[k * 384 + d];
            a2 += mk * uw1T[k * 384 + d];
        }
        ph1[half][d] = a1;
        ph2[half][d] = a2;
    }
    __syncthreads();
    if (half == 0) {
        h1s[d] = fmaxf(ph1[0][d] + ph1[1][d] + rb1[d], 0.f);
        h2s[d] = fmaxf(ph2[0][d] + ph2[1][d] + ub1[d], 0.f);
    }
    __syncthreads();
    if (t < 64) {
        int lane = t;
        float acc[8] = {};
        for (int dd = lane; dd < 384; dd += 64) {
            float v1 = h1s[dd], v2 = h2s[dd];
            #pragma unroll
            for (int o = 0; o < 6; ++o) acc[o] += v1 * rw2[o * 384 + dd];
            acc[6] += v2 * uw2[dd];
            acc[7] += v2 * uw2[384 + dd];
        }
        #pragma unroll
        for (int o = 0; o < 8; ++o)
            #pragma unroll
            for (int off = 32; off >= 1; off >>= 1) acc[o] += __shfl_xor(acc[o], off);
        if (lane == 0) {
            float r[6];
            for (int o = 0; o < 6; ++o) r[o] = acc[o] + rb2[o];
            float u0 = acc[6] + ub2[0], u1 = acc[7] + ub2[1];
            float dot12 = r[0] * r[3] + r[1] * r[4] + r[2] * r[5];
            float q2x = r[3] - dot12 * r[0], q2y = r[4] - dot12 * r[1], q2z = r[5] - dot12 * r[2];
            float q3x = r[1] * q2z - r[2] * q2y;
            float q3y = r[2] * q2x - r[0] * q2z;
            float q3z = r[0] * q2y - r[1] * q2x;
            float n1 = fmaxf(sqrtf(r[0]*r[0] + r[1]*r[1] + r[2]*r[2]), 1e-12f);
            float n2 = fmaxf(sqrtf(q2x*q2x + q2y*q2y + q2z*q2z), 1e-12f);
            float n3 = fmaxf(sqrtf(q3x*q3x + q3y*q3y + q3z*q3z), 1e-12f);
            out[b * 2 + 0] = 1.f / (1.f + expf(-u0));
            out[b * 2 + 1] = 1.f / (1.f + expf(-u1));
            float* R = out + B_ * 2 + b * 9;
            R[0] = r[0] / n1; R[1] = r[1] / n1; R[2] = r[2] / n1;
            R[3] = q2x / n2;  R[4] = q2y / n2;  R[5] = q2z / n2;
            R[6] = q3x / n3;  R[7] = q3y / n3;  R[8] = q3z / n3;
        }
    }
}

extern "C" void kernel_launch(void* const* d_in, const int* in_sizes, int n_in,
                              void* d_out, int out_size, void* d_ws, size_t ws_size,
                              hipStream_t stream)
{
    bfp rgb     = (bfp)d_in[0];
    const int* pos0 = (const int*)d_in[1];
    const int* pos1 = (const int*)d_in[2];
    bfp conv_w  = (bfp)d_in[3];
    bfp conv_b  = (bfp)d_in[4];
    bfp ext_w   = (bfp)d_in[5];
    bfp ext_b   = (bfp)d_in[6];
    bfp proj_w  = (bfp)d_in[7];
    bfp proj_b  = (bfp)d_in[8];
    bfp Wqkv    = (bfp)d_in[9];
    bfp bqkv    = (bfp)d_in[10];
    bfp Wo      = (bfp)d_in[11];
    bfp bo      = (bfp)d_in[12];
    bfp ln1g    = (bfp)d_in[13];
    bfp ln1b    = (bfp)d_in[14];
    bfp ln2g    = (bfp)d_in[15];
    bfp ln2b    = (bfp)d_in[16];
    bfp Wff1    = (bfp)d_in[17];
    bfp bff1    = (bfp)d_in[18];
    bfp Wff2    = (bfp)d_in[19];
    bfp bff2    = (bfp)d_in[20];
    bfp rw1     = (bfp)d_in[21];
    bfp rb1     = (bfp)d_in[22];
    bfp rw2     = (bfp)d_in[23];
    bfp rb2     = (bfp)d_in[24];
    bfp uw1     = (bfp)d_in[25];
    bfp ub1     = (bfp)d_in[26];
    bfp uw2     = (bfp)d_in[27];
    bfp ub2     = (bfp)d_in[28];

    float* ws = (float*)d_ws;
    float*  X      = ws;
    __bf16* PIMG   = (__bf16*)(ws + 1081344);
    float*  QKV    = ws + 2162688;
    __bf16* QKVb   = (__bf16*)QKV;
    float*  PP0    = ws + 3276800;
    float*  PP1    = ws + 4259840;
    __bf16* OBUFb  = (__bf16*)(ws + 5406720);
    __bf16* FFH16  = (__bf16*)(ws + 6144000);
    __bf16* WIN1F16= FFH16;
    float*  PF     = ws + 9027584;
    float*  F0PRE  = ws + 9031808;
    __bf16* Xb     = (__bf16*)(ws + 9130112);
    __bf16* projWb = (__bf16*)(ws + 9670784);
    __bf16* WqkvB  = (__bf16*)(ws + 10002560);
    __bf16* WoB    = (__bf16*)(ws + 10887296);
    __bf16* Wff1B  = (__bf16*)(ws + 11182208);
    __bf16* Wff2B  = (__bf16*)(ws + 12755072);
    __bf16* WpadC  = (__bf16*)(ws + 14327936);
    float*  RW1T   = ws + 14340224;
    float*  UW1T   = ws + 14487680;

    hipMemsetAsync(F0PRE, 0, 256 * 128 * sizeof(float), stream);

    prep_k<<<10262, 256, 0, stream>>>(proj_w, Wqkv, Wo, Wff1, Wff2,
                                      projWb, WqkvB, WoB, Wff1B, Wff2B,
                                      conv_w, WpadC, pos0, pos1, PF,
                                      rw1, uw1, RW1T, UW1T);
    pimg_k<<<7128, 256, 0, stream>>>(rgb, pos0, PIMG);
    convgemm_k<<<2048, 256, 0, stream>>>(PIMG, WpadC, conv_b, F0PRE);
    win1_k<<<(B_ * 10 * 1728 + 255) / 256, 256, 0, stream>>>(rgb, pos1, WIN1F16);
    gemm_bb_k<<<dim3(6, 20, 2), 256, 0, stream>>>(WIN1F16, projWb, nullptr, nullptr,
                                                  PP0, 2560, 384, 1728, 0, 0, 896);
    assemble_k<<<(B_ * S_ * D_ + 255) / 256, 256, 0, stream>>>(
        F0PRE, ext_w, ext_b, PP0, PP1, proj_b, PF, X, Xb);

    for (int i = 0; i < 4; ++i) {
        gemm_bb_k<<<dim3(18, 22), 256, 0, stream>>>(
            Xb, WqkvB + (size_t)i * 1152 * 384, bqkv + i * 1152, nullptr, QKVb,
            2816, 1152, 384, 0, 1, 0);
        attn_k<<<B_ * NHEAD_, 128, 0, stream>>>(QKVb, OBUFb);
        gemm_bb_k<<<dim3(6, 22, 2), 256, 0, stream>>>(
            OBUFb, WoB + (size_t)i * 384 * 384, nullptr, nullptr, QKV,
            2816, 384, 384, 0, 0, 192);
        ln_k<<<352, 512, 0, stream>>>(QKV, 2, X, bo + i * 384,
                                      ln1g + i * 384, ln1b + i * 384, X, Xb);
        gemm_bb128_k<<<dim3(16, 22), 256, 0, stream>>>(
            Xb, Wff1B + (size_t)i * 2048 * 384, bff1 + i * 2048, FFH16,
            2816, 2048, 384, 1, 1);
        gemm_bb_k<<<dim3(6, 22, 3), 256, 0, stream>>>(
            FFH16, Wff2B + (size_t)i * 384 * 2048, nullptr, nullptr, QKV,
            2816, 384, 2048, 0, 0, 704);
        ln_k<<<352, 512, 0, stream>>>(QKV, 3, X, bff2 + i * 384,
                                      ln2g + i * 384, ln2b + i * 384, X, Xb);
    }

    headfused_k<<<256, 768, 0, stream>>>(X, RW1T, rb1, UW1T, ub1,
                                         rw2, rb2, uw2, ub2, (float*)d_out);
}